// Round 1
// baseline (138549.451 us; speedup 1.0000x reference)
//
#include <hip/hip_runtime.h>
#include <cfloat>
#include <cmath>

namespace {

constexpr int Bn = 64;     // batch
constexpr int Sn = 128;    // encoder seq len
constexpr int En = 512;    // embedding dim
constexpr int Hn = 1024;   // hidden dim
constexpr int Vn = 10000;  // vocab
constexpr int Tn = 144;    // 1 + STEPS output positions
constexpr int DEC = 143;   // decode steps

__device__ __forceinline__ double sigd(double x) { return 1.0 / (1.0 + exp(-x)); }

// Zero h0(ping0), h1(ping0), c0, c1. 65536 threads, one element of each region per thread.
__global__ __launch_bounds__(256) void init_state(double* __restrict__ ws) {
    const size_t i = (size_t)blockIdx.x * blockDim.x + threadIdx.x;  // 0..65535
    const size_t BH = (size_t)Bn * Hn;                               // 65536
    ws[i] = 0.0;            // h0 ping 0
    ws[2 * BH + i] = 0.0;   // h1 ping 0
    ws[4 * BH + i] = 0.0;   // c0
    ws[5 * BH + i] = 0.0;   // c1
}

// One LSTM cell for all (b, j). Block = 64 batch lanes x 4 hidden units; grid = 256.
// LAYER0: input = emb[token] (fp32, gathered); else input = xin (fp64, [64][1024]).
// All accumulation in fp64 so the argmax token chain matches the fp64 numpy reference.
template<bool LAYER0>
__global__ __launch_bounds__(256) void cell_kernel(
    const float* __restrict__ emb,
    const int* __restrict__ tokbase, const int tok_stride, const int tok_off,
    const double* __restrict__ xin,
    const double* __restrict__ hin,
    double* __restrict__ hout,
    double* __restrict__ cst,
    const float* __restrict__ Wih,
    const float* __restrict__ Whh,
    const float* __restrict__ bih,
    const float* __restrict__ bhh)
{
    const int tid = (int)threadIdx.x;
    const int b = tid & 63;                       // lanes 0..63 share j -> uniform weight loads
    const int j = (int)blockIdx.x * 4 + (tid >> 6);
    constexpr int KX = LAYER0 ? En : Hn;

    // PyTorch gate row order: i, f, g, o
    const float* __restrict__ wxi = Wih + (size_t)(0 * Hn + j) * KX;
    const float* __restrict__ wxf = Wih + (size_t)(1 * Hn + j) * KX;
    const float* __restrict__ wxg = Wih + (size_t)(2 * Hn + j) * KX;
    const float* __restrict__ wxo = Wih + (size_t)(3 * Hn + j) * KX;
    const float* __restrict__ whi = Whh + (size_t)(0 * Hn + j) * Hn;
    const float* __restrict__ whf = Whh + (size_t)(1 * Hn + j) * Hn;
    const float* __restrict__ whg = Whh + (size_t)(2 * Hn + j) * Hn;
    const float* __restrict__ who = Whh + (size_t)(3 * Hn + j) * Hn;

    double ai = (double)bih[0 * Hn + j] + (double)bhh[0 * Hn + j];
    double af = (double)bih[1 * Hn + j] + (double)bhh[1 * Hn + j];
    double ag = (double)bih[2 * Hn + j] + (double)bhh[2 * Hn + j];
    double ao = (double)bih[3 * Hn + j] + (double)bhh[3 * Hn + j];

    if (LAYER0) {
        const int token = tokbase[b * tok_stride + tok_off];
        const float* __restrict__ xr = emb + (size_t)token * En;
        #pragma unroll 4
        for (int k = 0; k < KX; ++k) {
            const double xv = (double)xr[k];
            ai = fma(xv, (double)wxi[k], ai);
            af = fma(xv, (double)wxf[k], af);
            ag = fma(xv, (double)wxg[k], ag);
            ao = fma(xv, (double)wxo[k], ao);
        }
    } else {
        const double* __restrict__ xr = xin + (size_t)b * Hn;
        #pragma unroll 4
        for (int k = 0; k < KX; ++k) {
            const double xv = xr[k];
            ai = fma(xv, (double)wxi[k], ai);
            af = fma(xv, (double)wxf[k], af);
            ag = fma(xv, (double)wxg[k], ag);
            ao = fma(xv, (double)wxo[k], ao);
        }
    }
    {
        const double* __restrict__ hr = hin + (size_t)b * Hn;
        #pragma unroll 4
        for (int k = 0; k < Hn; ++k) {
            const double hv = hr[k];
            ai = fma(hv, (double)whi[k], ai);
            af = fma(hv, (double)whf[k], af);
            ag = fma(hv, (double)whg[k], ag);
            ao = fma(hv, (double)who[k], ao);
        }
    }

    const double ig = sigd(ai);
    const double fg = sigd(af);
    const double gg = tanh(ag);
    const double og = sigd(ao);
    const size_t idx = (size_t)b * Hn + j;
    const double cn = fg * cst[idx] + ig * gg;   // c is elementwise -> safe in place
    cst[idx] = cn;
    hout[idx] = og * tanh(cn);
}

// logits[b, v0..v0+3] = h[b,:] @ Wfc[v,:] + bfc[v]. Block = 64 lanes x 4 v-groups; grid = 625.
// Writes fp32 slice into d_out and fp64 copy for the argmax.
__global__ __launch_bounds__(256) void logits_kernel(
    const double* __restrict__ h,
    const float* __restrict__ Wfc,
    const float* __restrict__ bfc,
    float* __restrict__ outf,     // = d_out + t*Vn ; per-b stride Tn*Vn
    double* __restrict__ outd)    // [64][Vn]
{
    const int tid = (int)threadIdx.x;
    const int b = tid & 63;
    const int g = tid >> 6;
    const int v0 = (int)blockIdx.x * 16 + g * 4;
    const double* __restrict__ hr = h + (size_t)b * Hn;
    const float* __restrict__ w0 = Wfc + (size_t)(v0 + 0) * Hn;
    const float* __restrict__ w1 = Wfc + (size_t)(v0 + 1) * Hn;
    const float* __restrict__ w2 = Wfc + (size_t)(v0 + 2) * Hn;
    const float* __restrict__ w3 = Wfc + (size_t)(v0 + 3) * Hn;
    double a0 = (double)bfc[v0 + 0];
    double a1 = (double)bfc[v0 + 1];
    double a2 = (double)bfc[v0 + 2];
    double a3 = (double)bfc[v0 + 3];
    #pragma unroll 4
    for (int k = 0; k < Hn; ++k) {
        const double hv = hr[k];
        a0 = fma(hv, (double)w0[k], a0);
        a1 = fma(hv, (double)w1[k], a1);
        a2 = fma(hv, (double)w2[k], a2);
        a3 = fma(hv, (double)w3[k], a3);
    }
    double* od = outd + (size_t)b * Vn + v0;
    od[0] = a0; od[1] = a1; od[2] = a2; od[3] = a3;
    float* of = outf + (size_t)b * ((size_t)Tn * Vn) + v0;
    of[0] = (float)a0; of[1] = (float)a1; of[2] = (float)a2; of[3] = (float)a3;
}

// First-index argmax per batch row (matches jnp.argmax tie-breaking). One block per b.
__global__ __launch_bounds__(256) void argmax_kernel(
    const double* __restrict__ vals, const int n, const int rowstride, int* __restrict__ tok)
{
    __shared__ double sv[256];
    __shared__ int si[256];
    const int tid = (int)threadIdx.x;
    const int b = (int)blockIdx.x;
    const double* __restrict__ row = vals + (size_t)b * rowstride;
    double best = -DBL_MAX;
    int bi = 0x7fffffff;
    for (int k = tid; k < n; k += 256) {
        const double v = row[k];
        if (v > best) { best = v; bi = k; }   // strict > keeps earliest index in-thread
    }
    sv[tid] = best; si[tid] = bi;
    __syncthreads();
    for (int s = 128; s > 0; s >>= 1) {
        if (tid < s) {
            if (sv[tid + s] > sv[tid] || (sv[tid + s] == sv[tid] && si[tid + s] < si[tid])) {
                sv[tid] = sv[tid + s];
                si[tid] = si[tid + s];
            }
        }
        __syncthreads();
    }
    if (tid == 0) tok[b] = si[0];
}

} // namespace

extern "C" void kernel_launch(void* const* d_in, const int* in_sizes, int n_in,
                              void* d_out, int out_size, void* d_ws, size_t ws_size,
                              hipStream_t stream)
{
    const int*   x    = (const int*)d_in[0];
    const float* emb  = (const float*)d_in[1];
    const float* Wih0 = (const float*)d_in[2];
    const float* Whh0 = (const float*)d_in[3];
    const float* bih0 = (const float*)d_in[4];
    const float* bhh0 = (const float*)d_in[5];
    const float* Wih1 = (const float*)d_in[6];
    const float* Whh1 = (const float*)d_in[7];
    const float* bih1 = (const float*)d_in[8];
    const float* bhh1 = (const float*)d_in[9];
    const float* Wfc  = (const float*)d_in[10];
    const float* bfc  = (const float*)d_in[11];
    float* out = (float*)d_out;

    // ws layout (doubles): h0[2][64*1024] | h1[2][64*1024] | c0 | c1 | logits_d[64*10000] | tok[64] ints
    double* ws = (double*)d_ws;
    const size_t BH = (size_t)Bn * Hn;   // 65536
    double* h0   = ws;
    double* h1   = ws + 2 * BH;
    double* c0   = ws + 4 * BH;
    double* c1   = ws + 5 * BH;
    double* logd = ws + 6 * BH;
    int*    tok  = (int*)(ws + 6 * BH + (size_t)Bn * Vn);

    init_state<<<256, 256, 0, stream>>>(ws);

    int p = 0;
    // -------- encoder: 128 steps --------
    for (int t = 0; t < Sn; ++t) {
        cell_kernel<true><<<256, 256, 0, stream>>>(
            emb, x, Sn, t, nullptr,
            h0 + (size_t)p * BH, h0 + (size_t)(1 - p) * BH, c0, Wih0, Whh0, bih0, bhh0);
        cell_kernel<false><<<256, 256, 0, stream>>>(
            nullptr, nullptr, 0, 0, h0 + (size_t)(1 - p) * BH,
            h1 + (size_t)p * BH, h1 + (size_t)(1 - p) * BH, c1, Wih1, Whh1, bih1, bhh1);
        p ^= 1;
    }
    // first logits from final encoder hidden state; tok0 = argmax over the raw hidden state (quirk)
    logits_kernel<<<625, 256, 0, stream>>>(h1 + (size_t)p * BH, Wfc, bfc, out, logd);
    argmax_kernel<<<64, 256, 0, stream>>>(h1 + (size_t)p * BH, Hn, Hn, tok);

    // -------- decoder: 143 steps --------
    for (int s = 0; s < DEC; ++s) {
        cell_kernel<true><<<256, 256, 0, stream>>>(
            emb, tok, 1, 0, nullptr,
            h0 + (size_t)p * BH, h0 + (size_t)(1 - p) * BH, c0, Wih0, Whh0, bih0, bhh0);
        cell_kernel<false><<<256, 256, 0, stream>>>(
            nullptr, nullptr, 0, 0, h0 + (size_t)(1 - p) * BH,
            h1 + (size_t)p * BH, h1 + (size_t)(1 - p) * BH, c1, Wih1, Whh1, bih1, bhh1);
        p ^= 1;
        logits_kernel<<<625, 256, 0, stream>>>(
            h1 + (size_t)p * BH, Wfc, bfc, out + (size_t)(1 + s) * Vn, logd);
        argmax_kernel<<<64, 256, 0, stream>>>(logd, Vn, Vn, tok);
    }

    (void)in_sizes; (void)n_in; (void)out_size; (void)ws_size;
}

// Round 2
// 82588.763 us; speedup vs baseline: 1.6776x; 1.6776x over previous
//
#include <hip/hip_runtime.h>
#include <cfloat>
#include <cmath>

namespace {

constexpr int Bn = 64;     // batch
constexpr int Sn = 128;    // encoder seq len
constexpr int En = 512;    // embedding dim
constexpr int Hn = 1024;   // hidden dim
constexpr int Vn = 10000;  // vocab
constexpr int Tn = 144;    // 1 + STEPS output positions
constexpr int DEC = 143;   // decode steps
constexpr int ENC_CHUNK = 16;

__device__ __forceinline__ double sigd(double x) { return 1.0 / (1.0 + exp(-x)); }

// Zero the 6 state regions (h0 ping-pong, h1 ping-pong, c0, c1): 6*64*1024 doubles.
__global__ __launch_bounds__(256) void init_state(double* __restrict__ ws) {
    const size_t i = (size_t)blockIdx.x * blockDim.x + threadIdx.x;  // 0 .. 6*BH-1
    ws[i] = 0.0;
}

// Gather ENC_CHUNK encoder steps of embeddings into transposed fp32 x_t[ti][k][b].
__global__ __launch_bounds__(256) void gather_enc(
    const int* __restrict__ x, const float* __restrict__ emb,
    float* __restrict__ xt, const int t0)
{
    const int b  = (int)blockIdx.x & 63;
    const int ti = (int)blockIdx.x >> 6;
    const int token = x[b * Sn + t0 + ti];
    const float* __restrict__ er = emb + (size_t)token * En;
    float* __restrict__ xo = xt + (size_t)ti * En * 64;
    for (int k = (int)threadIdx.x; k < En; k += 256)
        xo[(size_t)k * 64 + b] = er[k];   // read coalesced; write small scatter (one-time)
}

// One LSTM cell. State layout is TRANSPOSED: h/c/x stored as [k][64] so lane=b is coalesced.
// Block = 256 threads = 4 waves; block computes ONE output unit j for all 64 b.
// The 4 waves split the k-dimension 4 ways; partials reduced through LDS.
// All accumulation fp64 (weights cvt f32->f64 per element) to keep the argmax token chain
// locked to the trajectory that round 1 validated.
template<typename XT, int KX>
__global__ __launch_bounds__(256) void cell_kernel(
    const XT*     __restrict__ xt,    // [KX][64]
    const double* __restrict__ hin,   // [Hn][64]
    double*       __restrict__ hout,  // [Hn][64]
    double*       __restrict__ cst,   // [Hn][64]
    const float*  __restrict__ Wih,   // [4Hn][KX] rows i,f,g,o
    const float*  __restrict__ Whh,   // [4Hn][Hn]
    const float*  __restrict__ bih,
    const float*  __restrict__ bhh)
{
    __shared__ double part[4][4][64];   // [wave][gate][b]
    const int tid = (int)threadIdx.x;
    const int b = tid & 63;
    const int w = tid >> 6;
    const int j = (int)blockIdx.x;

    double a0 = 0.0, a1 = 0.0, a2 = 0.0, a3 = 0.0;

    // ---- x part: K = KX, wave chunk KX/4 ----
    {
        constexpr int C = KX / 4;
        const int k0 = w * C;
        const float4* __restrict__ r0 = (const float4*)(Wih + (size_t)(0 * Hn + j) * KX + k0);
        const float4* __restrict__ r1 = (const float4*)(Wih + (size_t)(1 * Hn + j) * KX + k0);
        const float4* __restrict__ r2 = (const float4*)(Wih + (size_t)(2 * Hn + j) * KX + k0);
        const float4* __restrict__ r3 = (const float4*)(Wih + (size_t)(3 * Hn + j) * KX + k0);
        const XT* __restrict__ xp = xt + (size_t)k0 * 64 + b;
        #pragma unroll 2
        for (int i = 0; i < C / 4; ++i) {
            const float4 w0 = r0[i], w1 = r1[i], w2 = r2[i], w3 = r3[i];
            const double x0 = (double)xp[(size_t)(4 * i + 0) * 64];
            const double x1 = (double)xp[(size_t)(4 * i + 1) * 64];
            const double x2 = (double)xp[(size_t)(4 * i + 2) * 64];
            const double x3 = (double)xp[(size_t)(4 * i + 3) * 64];
            a0 = fma(x0, (double)w0.x, a0); a0 = fma(x1, (double)w0.y, a0);
            a0 = fma(x2, (double)w0.z, a0); a0 = fma(x3, (double)w0.w, a0);
            a1 = fma(x0, (double)w1.x, a1); a1 = fma(x1, (double)w1.y, a1);
            a1 = fma(x2, (double)w1.z, a1); a1 = fma(x3, (double)w1.w, a1);
            a2 = fma(x0, (double)w2.x, a2); a2 = fma(x1, (double)w2.y, a2);
            a2 = fma(x2, (double)w2.z, a2); a2 = fma(x3, (double)w2.w, a2);
            a3 = fma(x0, (double)w3.x, a3); a3 = fma(x1, (double)w3.y, a3);
            a3 = fma(x2, (double)w3.z, a3); a3 = fma(x3, (double)w3.w, a3);
        }
    }
    // ---- h part: K = Hn, wave chunk Hn/4 ----
    {
        constexpr int C = Hn / 4;
        const int k0 = w * C;
        const float4* __restrict__ r0 = (const float4*)(Whh + (size_t)(0 * Hn + j) * Hn + k0);
        const float4* __restrict__ r1 = (const float4*)(Whh + (size_t)(1 * Hn + j) * Hn + k0);
        const float4* __restrict__ r2 = (const float4*)(Whh + (size_t)(2 * Hn + j) * Hn + k0);
        const float4* __restrict__ r3 = (const float4*)(Whh + (size_t)(3 * Hn + j) * Hn + k0);
        const double* __restrict__ hp = hin + (size_t)k0 * 64 + b;
        #pragma unroll 2
        for (int i = 0; i < C / 4; ++i) {
            const float4 w0 = r0[i], w1 = r1[i], w2 = r2[i], w3 = r3[i];
            const double x0 = hp[(size_t)(4 * i + 0) * 64];
            const double x1 = hp[(size_t)(4 * i + 1) * 64];
            const double x2 = hp[(size_t)(4 * i + 2) * 64];
            const double x3 = hp[(size_t)(4 * i + 3) * 64];
            a0 = fma(x0, (double)w0.x, a0); a0 = fma(x1, (double)w0.y, a0);
            a0 = fma(x2, (double)w0.z, a0); a0 = fma(x3, (double)w0.w, a0);
            a1 = fma(x0, (double)w1.x, a1); a1 = fma(x1, (double)w1.y, a1);
            a1 = fma(x2, (double)w1.z, a1); a1 = fma(x3, (double)w1.w, a1);
            a2 = fma(x0, (double)w2.x, a2); a2 = fma(x1, (double)w2.y, a2);
            a2 = fma(x2, (double)w2.z, a2); a2 = fma(x3, (double)w2.w, a2);
            a3 = fma(x0, (double)w3.x, a3); a3 = fma(x1, (double)w3.y, a3);
            a3 = fma(x2, (double)w3.z, a3); a3 = fma(x3, (double)w3.w, a3);
        }
    }

    part[w][0][b] = a0; part[w][1][b] = a1; part[w][2][b] = a2; part[w][3][b] = a3;
    __syncthreads();

    if (tid < 64) {
        const int bb = tid;
        const double ai = (double)bih[0 * Hn + j] + (double)bhh[0 * Hn + j]
                        + part[0][0][bb] + part[1][0][bb] + part[2][0][bb] + part[3][0][bb];
        const double af = (double)bih[1 * Hn + j] + (double)bhh[1 * Hn + j]
                        + part[0][1][bb] + part[1][1][bb] + part[2][1][bb] + part[3][1][bb];
        const double ag = (double)bih[2 * Hn + j] + (double)bhh[2 * Hn + j]
                        + part[0][2][bb] + part[1][2][bb] + part[2][2][bb] + part[3][2][bb];
        const double ao = (double)bih[3 * Hn + j] + (double)bhh[3 * Hn + j]
                        + part[0][3][bb] + part[1][3][bb] + part[2][3][bb] + part[3][3][bb];
        const double ig = sigd(ai);
        const double fg = sigd(af);
        const double gg = tanh(ag);
        const double og = sigd(ao);
        const size_t idx = (size_t)j * 64 + bb;
        const double cn = fg * cst[idx] + ig * gg;
        cst[idx] = cn;
        hout[idx] = og * tanh(cn);
    }
}

// logits[b, v0..v0+3]; block = 4 waves k-splitting Hn; grid = Vn/4 = 2500.
// Writes fp32 directly into d_out at [b][t][v] (t folded into outf pointer).
__global__ __launch_bounds__(256) void logits_kernel(
    const double* __restrict__ h,     // [Hn][64]
    const float*  __restrict__ Wfc,   // [Vn][Hn]
    const float*  __restrict__ bfc,
    float*        __restrict__ outf)  // d_out + t*Vn ; b stride = Tn*Vn
{
    __shared__ double part[4][4][64];   // [wave][vi][b]
    const int tid = (int)threadIdx.x;
    const int b = tid & 63;
    const int w = tid >> 6;
    const int v0 = (int)blockIdx.x * 4;
    double a0 = 0.0, a1 = 0.0, a2 = 0.0, a3 = 0.0;
    const int k0 = w * (Hn / 4);
    const float4* __restrict__ r0 = (const float4*)(Wfc + (size_t)(v0 + 0) * Hn + k0);
    const float4* __restrict__ r1 = (const float4*)(Wfc + (size_t)(v0 + 1) * Hn + k0);
    const float4* __restrict__ r2 = (const float4*)(Wfc + (size_t)(v0 + 2) * Hn + k0);
    const float4* __restrict__ r3 = (const float4*)(Wfc + (size_t)(v0 + 3) * Hn + k0);
    const double* __restrict__ hp = h + (size_t)k0 * 64 + b;
    #pragma unroll 2
    for (int i = 0; i < Hn / 16; ++i) {
        const float4 w0 = r0[i], w1 = r1[i], w2 = r2[i], w3 = r3[i];
        const double x0 = hp[(size_t)(4 * i + 0) * 64];
        const double x1 = hp[(size_t)(4 * i + 1) * 64];
        const double x2 = hp[(size_t)(4 * i + 2) * 64];
        const double x3 = hp[(size_t)(4 * i + 3) * 64];
        a0 = fma(x0, (double)w0.x, a0); a0 = fma(x1, (double)w0.y, a0);
        a0 = fma(x2, (double)w0.z, a0); a0 = fma(x3, (double)w0.w, a0);
        a1 = fma(x0, (double)w1.x, a1); a1 = fma(x1, (double)w1.y, a1);
        a1 = fma(x2, (double)w1.z, a1); a1 = fma(x3, (double)w1.w, a1);
        a2 = fma(x0, (double)w2.x, a2); a2 = fma(x1, (double)w2.y, a2);
        a2 = fma(x2, (double)w2.z, a2); a2 = fma(x3, (double)w2.w, a2);
        a3 = fma(x0, (double)w3.x, a3); a3 = fma(x1, (double)w3.y, a3);
        a3 = fma(x2, (double)w3.z, a3); a3 = fma(x3, (double)w3.w, a3);
    }
    part[w][0][b] = a0; part[w][1][b] = a1; part[w][2][b] = a2; part[w][3][b] = a3;
    __syncthreads();
    const int vi = tid >> 6;
    const int bb = tid & 63;
    const double s = (double)bfc[v0 + vi]
                   + part[0][vi][bb] + part[1][vi][bb] + part[2][vi][bb] + part[3][vi][bb];
    outf[(size_t)bb * ((size_t)Tn * Vn) + v0 + vi] = (float)s;
}

// Fused first-index argmax (matches jnp.argmax) + embedding gather into x_t[k][b].
// One block per batch row b.
template<typename T>
__global__ __launch_bounds__(256) void argmax_gather(
    const T* __restrict__ vals, const int n, const int estride, const size_t bstride,
    const float* __restrict__ emb, float* __restrict__ xt)
{
    __shared__ double sv[256];
    __shared__ int si[256];
    __shared__ int stok;
    const int tid = (int)threadIdx.x;
    const int b = (int)blockIdx.x;
    const T* __restrict__ row = vals + (size_t)b * bstride;
    double best = -DBL_MAX;
    int bi = 0x7fffffff;
    for (int k = tid; k < n; k += 256) {
        const double v = (double)row[(size_t)k * estride];
        if (v > best) { best = v; bi = k; }   // strict > keeps earliest index in-thread
    }
    sv[tid] = best; si[tid] = bi;
    __syncthreads();
    for (int s = 128; s > 0; s >>= 1) {
        if (tid < s) {
            if (sv[tid + s] > sv[tid] || (sv[tid + s] == sv[tid] && si[tid + s] < si[tid])) {
                sv[tid] = sv[tid + s];
                si[tid] = si[tid + s];
            }
        }
        __syncthreads();
    }
    if (tid == 0) stok = si[0];
    __syncthreads();
    const float* __restrict__ er = emb + (size_t)stok * En;
    for (int k = tid; k < En; k += 256)
        xt[(size_t)k * 64 + b] = er[k];
}

} // namespace

extern "C" void kernel_launch(void* const* d_in, const int* in_sizes, int n_in,
                              void* d_out, int out_size, void* d_ws, size_t ws_size,
                              hipStream_t stream)
{
    const int*   x    = (const int*)d_in[0];
    const float* emb  = (const float*)d_in[1];
    const float* Wih0 = (const float*)d_in[2];
    const float* Whh0 = (const float*)d_in[3];
    const float* bih0 = (const float*)d_in[4];
    const float* bhh0 = (const float*)d_in[5];
    const float* Wih1 = (const float*)d_in[6];
    const float* Whh1 = (const float*)d_in[7];
    const float* bih1 = (const float*)d_in[8];
    const float* bhh1 = (const float*)d_in[9];
    const float* Wfc  = (const float*)d_in[10];
    const float* bfc  = (const float*)d_in[11];
    float* out = (float*)d_out;

    // ws (doubles): h0[2][BH] | h1[2][BH] | c0[BH] | c1[BH]  then fp32 xt[ENC_CHUNK][En][64]
    double* ws = (double*)d_ws;
    const size_t BH = (size_t)Bn * Hn;   // 65536
    double* h0 = ws;
    double* h1 = ws + 2 * BH;
    double* c0 = ws + 4 * BH;
    double* c1 = ws + 5 * BH;
    float*  xt = (float*)(ws + 6 * BH);  // 16*512*64 floats = 2 MB; total ws use ~5.3 MB

    init_state<<<1536, 256, 0, stream>>>(ws);   // zeros all 6 BH regions

    int p = 0;
    // -------- encoder: 128 steps, embedding gathers chunked x16 --------
    for (int t0 = 0; t0 < Sn; t0 += ENC_CHUNK) {
        gather_enc<<<ENC_CHUNK * 64, 256, 0, stream>>>(x, emb, xt, t0);
        for (int ti = 0; ti < ENC_CHUNK; ++ti) {
            cell_kernel<float, En><<<Hn, 256, 0, stream>>>(
                xt + (size_t)ti * En * 64,
                h0 + (size_t)p * BH, h0 + (size_t)(1 - p) * BH, c0,
                Wih0, Whh0, bih0, bhh0);
            cell_kernel<double, Hn><<<Hn, 256, 0, stream>>>(
                h0 + (size_t)(1 - p) * BH,
                h1 + (size_t)p * BH, h1 + (size_t)(1 - p) * BH, c1,
                Wih1, Whh1, bih1, bhh1);
            p ^= 1;
        }
    }

    // first logits row (t=0) + quirk token: argmax over the raw hidden state
    logits_kernel<<<2500, 256, 0, stream>>>(h1 + (size_t)p * BH, Wfc, bfc, out);
    argmax_gather<double><<<64, 256, 0, stream>>>(
        h1 + (size_t)p * BH, Hn, 64, 1, emb, xt);   // row base h1+b, elem stride 64

    // -------- decoder: 143 steps --------
    for (int s = 0; s < DEC; ++s) {
        cell_kernel<float, En><<<Hn, 256, 0, stream>>>(
            xt,
            h0 + (size_t)p * BH, h0 + (size_t)(1 - p) * BH, c0,
            Wih0, Whh0, bih0, bhh0);
        cell_kernel<double, Hn><<<Hn, 256, 0, stream>>>(
            h0 + (size_t)(1 - p) * BH,
            h1 + (size_t)p * BH, h1 + (size_t)(1 - p) * BH, c1,
            Wih1, Whh1, bih1, bhh1);
        p ^= 1;
        logits_kernel<<<2500, 256, 0, stream>>>(
            h1 + (size_t)p * BH, Wfc, bfc, out + (size_t)(1 + s) * Vn);
        if (s + 1 < DEC) {
            argmax_gather<float><<<64, 256, 0, stream>>>(
                out + (size_t)(1 + s) * Vn, Vn, 1, (size_t)Tn * Vn, emb, xt);
        }
    }

    (void)in_sizes; (void)n_in; (void)out_size; (void)ws_size;
}